// Round 6
// baseline (7207.549 us; speedup 1.0000x reference)
//
#include <hip/hip_runtime.h>
#include <math.h>

// ULOSD keypoint autoencoder, fp32.
// Round 6: LDS-tiled convolutions. Block = 16x16 output pixels, NCO output
// channels per thread in registers; input halo tile staged once to LDS
// (double-buffered CB-channel chunks). Per ci: 9 ds_reads feed 9*NCO FMAs with
// wave-uniform scalar-loaded weights. s1 tile 18x18 (PW=24: uniform 2-way bank
// aliasing = free). s2 tile 33x33 de-interleaved even/odd cols (PW=36: 2-way).
// Split-K via blockIdx.z + combine epilogue keeps every grid >= 512 blocks.

enum { ACT_ID = 0, ACT_LRELU = 1, ACT_SOFTPLUS = 2, ACT_RELU = 3 };

template<int ACT>
__device__ __forceinline__ float act_fn(float x) {
  if (ACT == ACT_LRELU)    return x >= 0.f ? x : 0.2f * x;
  if (ACT == ACT_SOFTPLUS) return fmaxf(x, 0.f) + log1pf(expf(-fabsf(x)));
  if (ACT == ACT_RELU)     return fmaxf(x, 0.f);
  return x;
}

// ---------------- LDS-tiled stride-1 3x3 SAME conv ----------------------------
// grid: x = tile index (ntx * nty), y = b*(Cout/NCO)+cog, z = K-slice
template<int ACT, int NCO, int CB, int KS>
__global__ __launch_bounds__(256)
void conv_s1_t(const float* __restrict__ in, const float* __restrict__ w,
               const float* __restrict__ bias, float* __restrict__ out,
               int Cin, int Cout, int H, int W, int ntx, size_t kstride) {
  constexpr int PW = 24, TILE = 18 * PW;
  __shared__ float sm[2][CB * TILE];
  const int cogs = Cout / NCO;
  const int by = blockIdx.y;
  const int b = by / cogs, cog = by - b * cogs;
  const int co0 = cog * NCO;
  const int ty0 = (blockIdx.x / ntx) * 16;
  const int tx0 = (blockIdx.x - (blockIdx.x / ntx) * ntx) * 16;
  const int tx = threadIdx.x & 15, ty = threadIdx.x >> 4;
  const int HW = H * W;
  const float* ib = in + (size_t)b * Cin * HW;
  const int nci = Cin / KS;
  const int ci0 = (KS > 1) ? (int)blockIdx.z * nci : 0;

  float acc[NCO];
  #pragma unroll
  for (int u = 0; u < NCO; ++u) acc[u] = 0.f;

  auto stage = [&](int sel, int cbase) {
    const int tot = CB * 324;           // 18*18 per channel
    for (int e = threadIdx.x; e < tot; e += 256) {
      const int ch = e / 324;
      const int rem = e - ch * 324;
      const int row = rem / 18;
      const int col = rem - row * 18;
      const int gy = ty0 - 1 + row;
      const int gx = tx0 - 1 + col;
      float v = 0.f;
      if (gy >= 0 && gy < H && gx >= 0 && gx < W)
        v = ib[(size_t)(cbase + ch) * HW + gy * W + gx];
      sm[sel][ch * TILE + row * PW + col] = v;
    }
  };

  stage(0, ci0);
  __syncthreads();
  const int nchunk = nci / CB;
  for (int t = 0; t < nchunk; ++t) {
    const int sel = t & 1;
    if (t + 1 < nchunk) stage(sel ^ 1, ci0 + (t + 1) * CB);
    #pragma unroll
    for (int c = 0; c < CB; ++c) {
      const float* sp = &sm[sel][c * TILE + ty * PW + tx];
      const float v00 = sp[0],      v01 = sp[1],      v02 = sp[2];
      const float v10 = sp[PW],     v11 = sp[PW+1],   v12 = sp[PW+2];
      const float v20 = sp[2*PW],   v21 = sp[2*PW+1], v22 = sp[2*PW+2];
      const int cg = ci0 + t * CB + c;
      #pragma unroll
      for (int u = 0; u < NCO; ++u) {
        const float* q = w + ((size_t)(co0 + u) * Cin + cg) * 9;
        acc[u] += v00*q[0] + v01*q[1] + v02*q[2]
                + v10*q[3] + v11*q[4] + v12*q[5]
                + v20*q[6] + v21*q[7] + v22*q[8];
      }
    }
    __syncthreads();
  }

  const int oy = ty0 + ty, ox = tx0 + tx;
  float* ob = out + ((KS > 1) ? (size_t)blockIdx.z * kstride : 0);
  #pragma unroll
  for (int u = 0; u < NCO; ++u) {
    float* op = ob + ((size_t)(b * Cout + co0 + u) * H + oy) * W + ox;
    if constexpr (KS > 1) *op = acc[u];
    else                  *op = act_fn<ACT>(acc[u] + bias[co0 + u]);
  }
}

// ---------------- LDS-tiled stride-2 3x3 SAME conv (pad 0/1) -------------------
// Input tile 33x33, stored de-interleaved: even cols at [0..16], odd at [17..32].
template<int ACT, int NCO, int CB, int KS>
__global__ __launch_bounds__(256)
void conv_s2_t(const float* __restrict__ in, const float* __restrict__ w,
               const float* __restrict__ bias, float* __restrict__ out,
               int Cin, int Cout, int H, int W, int ntx, size_t kstride) {
  constexpr int PW = 36, TILE = 33 * PW, EOFF = 17;
  __shared__ float sm[2][CB * TILE];
  const int Ho = H >> 1, Wo = W >> 1;
  const int cogs = Cout / NCO;
  const int by = blockIdx.y;
  const int b = by / cogs, cog = by - b * cogs;
  const int co0 = cog * NCO;
  const int ty0 = (blockIdx.x / ntx) * 16;        // output tile origin
  const int tx0 = (blockIdx.x - (blockIdx.x / ntx) * ntx) * 16;
  const int tx = threadIdx.x & 15, ty = threadIdx.x >> 4;
  const int HW = H * W;
  const float* ib = in + (size_t)b * Cin * HW;
  const int nci = Cin / KS;
  const int ci0 = (KS > 1) ? (int)blockIdx.z * nci : 0;

  float acc[NCO];
  #pragma unroll
  for (int u = 0; u < NCO; ++u) acc[u] = 0.f;

  auto stage = [&](int sel, int cbase) {
    const int tot = CB * 1089;          // 33*33 per channel
    for (int e = threadIdx.x; e < tot; e += 256) {
      const int ch = e / 1089;
      const int rem = e - ch * 1089;
      const int row = rem / 33;
      const int col = rem - row * 33;
      const int gy = 2 * ty0 + row;
      const int gx = 2 * tx0 + col;
      float v = 0.f;
      if (gy < H && gx < W)
        v = ib[(size_t)(cbase + ch) * HW + gy * W + gx];
      const int pos = (col & 1) ? (EOFF + (col >> 1)) : (col >> 1);
      sm[sel][ch * TILE + row * PW + pos] = v;
    }
  };

  stage(0, ci0);
  __syncthreads();
  const int nchunk = nci / CB;
  for (int t = 0; t < nchunk; ++t) {
    const int sel = t & 1;
    if (t + 1 < nchunk) stage(sel ^ 1, ci0 + (t + 1) * CB);
    #pragma unroll
    for (int c = 0; c < CB; ++c) {
      const float* sp = &sm[sel][c * TILE + (2 * ty) * PW];
      const float v00 = sp[tx],        v01 = sp[EOFF+tx],        v02 = sp[tx+1];
      const float v10 = sp[PW+tx],     v11 = sp[PW+EOFF+tx],     v12 = sp[PW+tx+1];
      const float v20 = sp[2*PW+tx],   v21 = sp[2*PW+EOFF+tx],   v22 = sp[2*PW+tx+1];
      const int cg = ci0 + t * CB + c;
      #pragma unroll
      for (int u = 0; u < NCO; ++u) {
        const float* q = w + ((size_t)(co0 + u) * Cin + cg) * 9;
        acc[u] += v00*q[0] + v01*q[1] + v02*q[2]
                + v10*q[3] + v11*q[4] + v12*q[5]
                + v20*q[6] + v21*q[7] + v22*q[8];
      }
    }
    __syncthreads();
  }

  const int oy = ty0 + ty, ox = tx0 + tx;
  float* ob = out + ((KS > 1) ? (size_t)blockIdx.z * kstride : 0);
  #pragma unroll
  for (int u = 0; u < NCO; ++u) {
    float* op = ob + ((size_t)(b * Cout + co0 + u) * Ho + oy) * Wo + ox;
    if constexpr (KS > 1) *op = acc[u];
    else                  *op = act_fn<ACT>(acc[u] + bias[co0 + u]);
  }
}

// ---------------- direct stride-1 conv (e0 only: Cin=3) ------------------------
template<int ACT, int NC, int CPT>
__global__ __launch_bounds__(256)
void conv_s1(const float* __restrict__ in, const float* __restrict__ w,
             const float* __restrict__ bias, float* __restrict__ out,
             int Cin, int Cout, int H, int W) {
  const int cogs = Cout / NC;
  const int gx  = blockIdx.x;
  const int cog = gx % cogs;
  const int b   = gx / cogs;
  const int co0 = cog * NC;
  const int Wq  = W / CPT;
  const int items = H * Wq;
  const int item  = blockIdx.y * 256 + threadIdx.x;
  if (item >= items) return;
  const int y  = item / Wq;
  const int x0 = (item - y * Wq) * CPT;

  const int HW = H * W;
  const float* ib = in + (size_t)b * Cin * HW;

  const bool okT = (y > 0), okB = (y < H - 1);
  const bool okL = (x0 > 0), okR = (x0 + CPT < W);
  const int ym = okT ? (y - 1) : 0;
  const int yp = okB ? (y + 1) : 0;
  const int xl = okL ? (x0 - 1) : 0;
  const int xr = okR ? (x0 + CPT) : 0;

  float acc[NC][CPT];
  #pragma unroll
  for (int u = 0; u < NC; ++u) {
    #pragma unroll
    for (int q = 0; q < CPT; ++q) acc[u][q] = 0.f;
  }

  for (int ci = 0; ci < Cin; ++ci) {
    const float* p = ib + ci * HW;
    #pragma unroll
    for (int dy = 0; dy < 3; ++dy) {
      const int  ry    = (dy == 0) ? ym : ((dy == 1) ? y : yp);
      const bool okRow = (dy == 0) ? okT : ((dy == 1) ? true : okB);
      const float* r = p + ry * W;
      float v[CPT + 2];
      float  lf = r[xl];
      float4 m  = *(const float4*)(r + x0);
      float  rf = r[xr];
      v[0] = (okRow && okL) ? lf : 0.f;
      v[1] = okRow ? m.x : 0.f;
      v[2] = okRow ? m.y : 0.f;
      v[3] = okRow ? m.z : 0.f;
      v[4] = okRow ? m.w : 0.f;
      v[5] = (okRow && okR) ? rf : 0.f;
      #pragma unroll
      for (int u = 0; u < NC; ++u) {
        const float* wp = w + ((size_t)(co0 + u) * Cin + ci) * 9 + dy * 3;
        const float w0 = wp[0], w1 = wp[1], w2 = wp[2];
        #pragma unroll
        for (int q = 0; q < CPT; ++q)
          acc[u][q] += v[q] * w0 + v[q + 1] * w1 + v[q + 2] * w2;
      }
    }
  }

  #pragma unroll
  for (int u = 0; u < NC; ++u) {
    const float bv = bias[co0 + u];
    float* op = out + ((size_t)(b * Cout + co0 + u) * H + y) * W + x0;
    float4 r4;
    r4.x = act_fn<ACT>(acc[u][0] + bv);
    r4.y = act_fn<ACT>(acc[u][1] + bv);
    r4.z = act_fn<ACT>(acc[u][2] + bv);
    r4.w = act_fn<ACT>(acc[u][3] + bv);
    *(float4*)op = r4;
  }
}

// ---------------- stride-2 3x3 SAME transposed conv ----------------------------
template<int ACT, int NC>
__global__ __launch_bounds__(256)
void tconv(const float* __restrict__ in, const float* __restrict__ w,
           const float* __restrict__ bias, float* __restrict__ out,
           int Cin, int Cout, int Hin) {
  const int cogs = Cout / NC;
  const int gx  = blockIdx.x;
  const int cog = gx % cogs;
  const int b   = gx / cogs;
  const int co0 = cog * NC;
  const int items = Hin * Hin;
  const int item  = blockIdx.y * 256 + threadIdx.x;
  if (item >= items) return;
  const int i = item / Hin;
  const int j = item - i * Hin;

  const float* ib = in + (size_t)b * Cin * items;
  const bool okT = (i > 0), okL = (j > 0);
  const int im = okT ? i - 1 : 0;
  const int jm = okL ? j - 1 : 0;

  float a00[NC], a01[NC], a10[NC], a11[NC];
  #pragma unroll
  for (int u = 0; u < NC; ++u) { a00[u]=0.f; a01[u]=0.f; a10[u]=0.f; a11[u]=0.f; }

  auto load4 = [&](float* v, int ci) {
    const float* p = ib + ci * items;
    v[0] = p[im*Hin + jm];
    v[1] = p[im*Hin + j];
    v[2] = p[i*Hin + jm];
    v[3] = p[i*Hin + j];
  };
  auto fma4 = [&](float* v, int ci) {
    float xtl = (okT && okL) ? v[0] : 0.f;
    float xtr = okT ? v[1] : 0.f;
    float xbl = okL ? v[2] : 0.f;
    float xbr = v[3];
    #pragma unroll
    for (int u = 0; u < NC; ++u) {
      const float* wp = w + ((size_t)(co0 + u) * Cin + ci) * 9;
      const float w00 = wp[0], w01 = wp[1], w02 = wp[2];
      const float w10 = wp[3], w11 = wp[4], w12 = wp[5];
      const float w20 = wp[6], w21 = wp[7], w22 = wp[8];
      a00[u] += xtl*w00 + xtr*w02 + xbl*w20 + xbr*w22;
      a01[u] += xtr*w01 + xbr*w21;
      a10[u] += xbl*w10 + xbr*w12;
      a11[u] += xbr*w11;
    }
  };

  float va[4], vb[4];
  load4(va, 0);
  int ci = 0;
  while (true) {
    if (ci + 1 < Cin) load4(vb, ci + 1);
    fma4(va, ci);
    ++ci; if (ci >= Cin) break;
    if (ci + 1 < Cin) load4(va, ci + 1);
    fma4(vb, ci);
    ++ci; if (ci >= Cin) break;
  }

  const int Ho = Hin * 2;
  #pragma unroll
  for (int u = 0; u < NC; ++u) {
    const float bv = bias[co0 + u];
    float* op = out + (size_t)(b * Cout + co0 + u) * Ho * Ho + (2*i) * Ho + 2*j;
    float2 t0, t1;
    t0.x = act_fn<ACT>(a00[u] + bv); t0.y = act_fn<ACT>(a01[u] + bv);
    t1.x = act_fn<ACT>(a10[u] + bv); t1.y = act_fn<ACT>(a11[u] + bv);
    *(float2*)op = t0;
    *(float2*)(op + Ho) = t1;
  }
}

// ---------------- split-K combine epilogues ------------------------------------
template<int ACT>
__global__ __launch_bounds__(256)
void combine2(const float* __restrict__ P0, const float* __restrict__ P1,
              const float* __restrict__ bias, float* __restrict__ out,
              int C, int HW, int n4) {
  const int i = blockIdx.x * 256 + threadIdx.x;
  if (i >= n4) return;
  const int e = i * 4;
  const int c = (e / HW) % C;
  float4 a = ((const float4*)P0)[i];
  float4 b = ((const float4*)P1)[i];
  const float bv = bias[c];
  float4 r;
  r.x = act_fn<ACT>(a.x + b.x + bv);
  r.y = act_fn<ACT>(a.y + b.y + bv);
  r.z = act_fn<ACT>(a.z + b.z + bv);
  r.w = act_fn<ACT>(a.w + b.w + bv);
  ((float4*)out)[i] = r;
}

template<int ACT>
__global__ __launch_bounds__(256)
void combine4(const float* __restrict__ P, const float* __restrict__ bias,
              float* __restrict__ out, int C, int HW, int n4, int ks4) {
  const int i = blockIdx.x * 256 + threadIdx.x;
  if (i >= n4) return;
  const int e = i * 4;
  const int c = (e / HW) % C;
  float4 a0 = ((const float4*)P)[i];
  float4 a1 = ((const float4*)P)[i + ks4];
  float4 a2 = ((const float4*)P)[i + 2 * ks4];
  float4 a3 = ((const float4*)P)[i + 3 * ks4];
  const float bv = bias[c];
  float4 r;
  r.x = act_fn<ACT>(a0.x + a1.x + a2.x + a3.x + bv);
  r.y = act_fn<ACT>(a0.y + a1.y + a2.y + a3.y + bv);
  r.z = act_fn<ACT>(a0.z + a1.z + a2.z + a3.z + bv);
  r.w = act_fn<ACT>(a0.w + a1.w + a2.w + a3.w + bv);
  ((float4*)out)[i] = r;
}

// ---------------- keypoint reductions ------------------------------------------
__global__ __launch_bounds__(64)
void kp_reduce(const float* __restrict__ R, float* __restrict__ S,
               float* __restrict__ Sh, float* __restrict__ Sw) {
  const int bk = blockIdx.x;
  const int t = threadIdx.x;
  const float* p = R + (size_t)bk * 256;
  float s = 0.f, sh = 0.f, sw = 0.f;
  #pragma unroll
  for (int q = 0; q < 4; ++q) {
    int idx = t + q * 64;
    float v = p[idx];
    s  += v;
    sh += v * (float)(idx >> 4);
    sw += v * (float)(idx & 15);
  }
  #pragma unroll
  for (int off = 32; off > 0; off >>= 1) {
    s  += __shfl_down(s, off);
    sh += __shfl_down(sh, off);
    sw += __shfl_down(sw, off);
  }
  if (t == 0) { S[bk] = s; Sh[bk] = sh; Sw[bk] = sw; }
}

__global__ __launch_bounds__(256)
void kp_maps(const float* __restrict__ S, const float* __restrict__ Sh,
             const float* __restrict__ Sw, float* __restrict__ maps, int K) {
  const int bk = blockIdx.x;
  const int b = bk / K;
  const int t = threadIdx.x;
  const float s   = S[bk];
  const float den = S[b * K + (K - 1)];
  const float mu  = s * (1.0f / 256.0f);
  const float c0  = Sh[bk] / den;
  const float c1  = Sw[bk] / den;
  const float u = (float)(t >> 4);
  const float v = (float)(t & 15);
  const float d2 = (u - c0) * (u - c0) + (v - c1) * (v - c1);
  maps[(size_t)bk * 256 + t] = mu * expf(-0.5f * d2);
}

extern "C" void kernel_launch(void* const* d_in, const int* in_sizes, int n_in,
                              void* d_out, int out_size, void* d_ws, size_t ws_size,
                              hipStream_t stream) {
  const int B = 32;  // 4 * 8
  const float* x = (const float*)d_in[0];
  const float* ew[7]; const float* eb[7];
  for (int j = 0; j < 7; ++j) { ew[j] = (const float*)d_in[1 + 2*j]; eb[j] = (const float*)d_in[2 + 2*j]; }
  const float* dw[6]; const float* db[6];
  for (int j = 0; j < 6; ++j) { dw[j] = (const float*)d_in[15 + 2*j]; db[j] = (const float*)d_in[16 + 2*j]; }

  float* ws   = (float*)d_ws;
  float* bufA = ws;                       // 16,777,216 floats
  float* bufB = bufA + 16777216;
  float* R    = bufB + 16777216;          // 1,048,576
  float* maps = R + 1048576;
  float* S    = maps + 1048576;           // 4096
  float* Sh   = S + 4096;
  float* Sw   = Sh + 4096;
  float* outp = (float*)d_out;

  dim3 blk(256);

  // ---- encoder ----
  // e0: 3->32 @128x128 direct (Cin too small for tiling)
  conv_s1<ACT_ID,8,4><<<dim3(B*4, 16), blk, 0, stream>>>(x, ew[0], eb[0], bufA, 3, 32, 128, 128);
  // e1: 32->32 @128x128, tiled. grid (64 tiles, 32) = 2048 blocks
  conv_s1_t<ACT_ID,32,8,1><<<dim3(64, B*1), blk, 0, stream>>>(bufA, ew[1], eb[1], bufB, 32, 32, 128, 128, 8, 0);
  // e2: 32->64 s2 128->64, tiled. grid (16, 64) = 1024
  conv_s2_t<ACT_LRELU,32,4,1><<<dim3(16, B*2), blk, 0, stream>>>(bufB, ew[2], eb[2], bufA, 32, 64, 128, 128, 4, 0);
  // e3: 64->64 @64x64, tiled. grid (16, 64) = 1024
  conv_s1_t<ACT_LRELU,32,8,1><<<dim3(16, B*2), blk, 0, stream>>>(bufA, ew[3], eb[3], bufB, 64, 64, 64, 64, 4, 0);
  // e4: 64->128 s2 64->32, tiled. grid (4, 256) = 1024
  conv_s2_t<ACT_LRELU,16,4,1><<<dim3(4, B*8), blk, 0, stream>>>(bufB, ew[4], eb[4], bufA, 64, 128, 64, 64, 2, 0);
  // e5: 128->128 @32x32, tiled, split-K=2. grid (4, 128, 2) = 1024
  float* P5 = bufA + 8388608;             // 2 x 4,194,304 (bufA input only uses 4.19M)
  conv_s1_t<ACT_LRELU,32,8,2><<<dim3(4, B*4, 2), blk, 0, stream>>>(bufA, ew[5], eb[5], P5, 128, 128, 32, 32, 2, 4194304);
  combine2<ACT_LRELU><<<dim3(4096), blk, 0, stream>>>(P5, P5 + 4194304, eb[5], bufB, 128, 1024, 1048576);
  // e6: 128->128 s2 32->16, tiled, split-K=4. grid (1, 128, 4) = 512
  float* P6 = bufA;                       // 4 x 1,048,576 (bufA fully dead now)
  conv_s2_t<ACT_SOFTPLUS,32,4,4><<<dim3(1, B*4, 4), blk, 0, stream>>>(bufB, ew[6], eb[6], P6, 128, 128, 32, 32, 1, 1048576);
  combine4<ACT_SOFTPLUS><<<dim3(1024), blk, 0, stream>>>(P6, eb[6], R, 128, 256, 262144, 262144);

  // ---- keypoint bottleneck ----
  kp_reduce<<<dim3(B*128), dim3(64), 0, stream>>>(R, S, Sh, Sw);
  kp_maps  <<<dim3(B*128), blk, 0, stream>>>(S, Sh, Sw, maps, 128);

  // ---- decoder ----
  // d0: tconv 128->64 @16->32 direct. grid (1024, 1)
  tconv<ACT_RELU,2><<<dim3(B*32, 1), blk, 0, stream>>>(maps, dw[0], db[0], bufA, 128, 64, 16);
  // d1: 64->64 @32x32, tiled, split-K=2. grid (4, 128, 2) = 1024
  float* PD1 = bufA + 4194304;            // 2 x 2,097,152 (d1 input uses first 2.1M)
  conv_s1_t<ACT_RELU,16,8,2><<<dim3(4, B*4, 2), blk, 0, stream>>>(bufA, dw[1], db[1], PD1, 64, 64, 32, 32, 2, 2097152);
  combine2<ACT_RELU><<<dim3(2048), blk, 0, stream>>>(PD1, PD1 + 2097152, db[1], bufB, 64, 1024, 524288);
  // d2: tconv 64->32 @32->64 direct
  tconv<ACT_RELU,4><<<dim3(B*8, 4), blk, 0, stream>>>(bufB, dw[2], db[2], bufA, 64, 32, 32);
  // d3: 32->32 @64x64, tiled. grid (16, 64) = 1024
  conv_s1_t<ACT_RELU,16,8,1><<<dim3(16, B*2), blk, 0, stream>>>(bufA, dw[3], db[3], bufB, 32, 32, 64, 64, 4, 0);
  // d4: tconv 32->16 @64->128 direct
  tconv<ACT_RELU,8><<<dim3(B*2, 16), blk, 0, stream>>>(bufB, dw[4], db[4], bufA, 32, 16, 64);
  // d5: 16->16 @128x128, tiled. grid (64, 32) = 2048
  conv_s1_t<ACT_RELU,16,8,1><<<dim3(64, B*1), blk, 0, stream>>>(bufA, dw[5], db[5], outp, 16, 16, 128, 128, 8, 0);
}

// Round 7
// 1522.438 us; speedup vs baseline: 4.7342x; 4.7342x over previous
//
#include <hip/hip_runtime.h>
#include <math.h>

// ULOSD keypoint autoencoder, fp32 direct convolutions.
// Round 7: revert LDS tiling (r6: 12% occ, 7.5M LDS conflicts, 27% VALU).
// Attack the VALU instruction mix instead (r2 evidence: only ~50% of VALU ops
// were MACs): (1) strict fmaf chains, (2) interior fast path with NO boundary
// cndmasks, (3) compile-time shapes so all 9 taps are base+immediate-offset
// loads. Weights stay wave-uniform (blockIdx-derived co-group -> s_loads).

enum { ACT_ID = 0, ACT_LRELU = 1, ACT_SOFTPLUS = 2, ACT_RELU = 3 };

template<int ACT>
__device__ __forceinline__ float act_fn(float x) {
  if (ACT == ACT_LRELU)    return x >= 0.f ? x : 0.2f * x;
  if (ACT == ACT_SOFTPLUS) return fmaxf(x, 0.f) + log1pf(expf(-fabsf(x)));
  if (ACT == ACT_RELU)     return fmaxf(x, 0.f);
  return x;
}

// ---------------- stride-1 3x3 SAME conv, NC couts x CPT cols per thread -------
template<int ACT, int NC, int CPT, int CIN, int COUT, int HH, int WW>
__global__ __launch_bounds__(256)
void conv_s1(const float* __restrict__ in, const float* __restrict__ w,
             const float* __restrict__ bias, float* __restrict__ out) {
  constexpr int cogs = COUT / NC;
  constexpr int HW = HH * WW;
  constexpr int Wq = WW / CPT;
  const int gx  = blockIdx.x;
  const int cog = gx % cogs;
  const int b   = gx / cogs;
  const int co0 = cog * NC;
  const int item = blockIdx.y * 256 + threadIdx.x;
  const int y  = item / Wq;
  const int x0 = (item - y * Wq) * CPT;
  const float* bp = in + (size_t)b * CIN * HW + y * WW + x0;

  float acc[NC][CPT];
#pragma unroll
  for (int u = 0; u < NC; ++u) {
#pragma unroll
    for (int q = 0; q < CPT; ++q) acc[u][q] = 0.f;
  }

  float v[3][CPT + 2];

  auto fma_all = [&](int ci) {
#pragma unroll
    for (int u = 0; u < NC; ++u) {
      const float* q = w + ((size_t)(co0 + u) * CIN + ci) * 9;
#pragma unroll
      for (int dy = 0; dy < 3; ++dy) {
        const float w0 = q[dy * 3], w1 = q[dy * 3 + 1], w2 = q[dy * 3 + 2];
#pragma unroll
        for (int t = 0; t < CPT; ++t) {
          acc[u][t] = fmaf(v[dy][t],     w0, acc[u][t]);
          acc[u][t] = fmaf(v[dy][t + 1], w1, acc[u][t]);
          acc[u][t] = fmaf(v[dy][t + 2], w2, acc[u][t]);
        }
      }
    }
  };

  const bool okT = (y > 0), okB = (y < HH - 1);
  const bool okL = (x0 > 0), okR = (x0 + CPT < WW);

  if (okT && okB && okL && okR) {
    // interior fast path: raw loads, immediate offsets, zero masks
    for (int ci = 0; ci < CIN; ++ci) {
      const float* p = bp + (size_t)ci * HW;
#pragma unroll
      for (int dy = 0; dy < 3; ++dy) {
        const float* r = p + (dy - 1) * WW;
        v[dy][0] = r[-1];
        if constexpr (CPT == 4) {
          float4 m = *(const float4*)r;
          v[dy][1] = m.x; v[dy][2] = m.y; v[dy][3] = m.z; v[dy][4] = m.w;
        } else if constexpr (CPT == 2) {
          float2 m = *(const float2*)r;
          v[dy][1] = m.x; v[dy][2] = m.y;
        } else {
          v[dy][1] = r[0];
        }
        v[dy][CPT + 1] = r[CPT];
      }
      fma_all(ci);
    }
  } else {
    // boundary path: clamped addresses + masks (edge tiles only)
    const int ro0 = okT ? -WW : 0;
    const int ro2 = okB ?  WW : 0;
    const int xlo = okL ? -1 : 0;
    const int xro = okR ? CPT : 0;
    for (int ci = 0; ci < CIN; ++ci) {
      const float* p = bp + (size_t)ci * HW;
#pragma unroll
      for (int dy = 0; dy < 3; ++dy) {
        const int  ro    = (dy == 0) ? ro0 : ((dy == 1) ? 0 : ro2);
        const bool okRow = (dy == 0) ? okT : ((dy == 1) ? true : okB);
        const float* r = p + ro;
        float lf = r[xlo];
        v[dy][0] = (okRow && okL) ? lf : 0.f;
#pragma unroll
        for (int t = 0; t < CPT; ++t) {
          float mv = r[t];
          v[dy][1 + t] = okRow ? mv : 0.f;
        }
        float rf = r[xro];
        v[dy][CPT + 1] = (okRow && okR) ? rf : 0.f;
      }
      fma_all(ci);
    }
  }

#pragma unroll
  for (int u = 0; u < NC; ++u) {
    const float bv = bias[co0 + u];
    float* op = out + ((size_t)(b * COUT + co0 + u) * HH + y) * WW + x0;
    if constexpr (CPT == 4) {
      float4 r4;
      r4.x = act_fn<ACT>(acc[u][0] + bv); r4.y = act_fn<ACT>(acc[u][1] + bv);
      r4.z = act_fn<ACT>(acc[u][2] + bv); r4.w = act_fn<ACT>(acc[u][3] + bv);
      *(float4*)op = r4;
    } else if constexpr (CPT == 2) {
      float2 r2;
      r2.x = act_fn<ACT>(acc[u][0] + bv); r2.y = act_fn<ACT>(acc[u][1] + bv);
      *(float2*)op = r2;
    } else {
      op[0] = act_fn<ACT>(acc[u][0] + bv);
    }
  }
}

// ---------------- stride-2 3x3 SAME conv (pad_before=0, pad_after=1) -----------
template<int ACT, int NC, int CPT, int CIN, int COUT, int HH, int WW>
__global__ __launch_bounds__(256)
void conv_s2(const float* __restrict__ in, const float* __restrict__ w,
             const float* __restrict__ bias, float* __restrict__ out) {
  constexpr int Ho = HH / 2, Wo = WW / 2;
  constexpr int cogs = COUT / NC;
  constexpr int HW = HH * WW;
  constexpr int Wq = Wo / CPT;
  const int gx  = blockIdx.x;
  const int cog = gx % cogs;
  const int b   = gx / cogs;
  const int co0 = cog * NC;
  const int item = blockIdx.y * 256 + threadIdx.x;
  const int y  = item / Wq;
  const int x0 = (item - y * Wq) * CPT;
  const int ix = 2 * x0;
  const float* bp = in + (size_t)b * CIN * HW + (2 * y) * WW + ix;

  float acc[NC][CPT];
#pragma unroll
  for (int u = 0; u < NC; ++u) {
#pragma unroll
    for (int q = 0; q < CPT; ++q) acc[u][q] = 0.f;
  }

  float v[3][2 * CPT + 1];

  auto fma_all = [&](int ci) {
#pragma unroll
    for (int u = 0; u < NC; ++u) {
      const float* q = w + ((size_t)(co0 + u) * CIN + ci) * 9;
#pragma unroll
      for (int dy = 0; dy < 3; ++dy) {
        const float w0 = q[dy * 3], w1 = q[dy * 3 + 1], w2 = q[dy * 3 + 2];
#pragma unroll
        for (int t = 0; t < CPT; ++t) {
          acc[u][t] = fmaf(v[dy][2 * t],     w0, acc[u][t]);
          acc[u][t] = fmaf(v[dy][2 * t + 1], w1, acc[u][t]);
          acc[u][t] = fmaf(v[dy][2 * t + 2], w2, acc[u][t]);
        }
      }
    }
  };

  const bool okB = (2 * y + 2 < HH);
  const bool okR = (ix + 2 * CPT < WW);

  if (okB && okR) {
    for (int ci = 0; ci < CIN; ++ci) {
      const float* p = bp + (size_t)ci * HW;
#pragma unroll
      for (int dy = 0; dy < 3; ++dy) {
        const float* r = p + dy * WW;
        if constexpr (CPT == 4) {
          float4 m0 = *(const float4*)r;
          float4 m1 = *(const float4*)(r + 4);
          v[dy][0]=m0.x; v[dy][1]=m0.y; v[dy][2]=m0.z; v[dy][3]=m0.w;
          v[dy][4]=m1.x; v[dy][5]=m1.y; v[dy][6]=m1.z; v[dy][7]=m1.w;
        } else if constexpr (CPT == 2) {
          float4 m0 = *(const float4*)r;
          v[dy][0]=m0.x; v[dy][1]=m0.y; v[dy][2]=m0.z; v[dy][3]=m0.w;
        } else {
          float2 m0 = *(const float2*)r;
          v[dy][0]=m0.x; v[dy][1]=m0.y;
        }
        v[dy][2 * CPT] = r[2 * CPT];
      }
      fma_all(ci);
    }
  } else {
    const int ro2 = okB ? 2 * WW : 0;
    const int xro = okR ? 2 * CPT : 0;
    for (int ci = 0; ci < CIN; ++ci) {
      const float* p = bp + (size_t)ci * HW;
#pragma unroll
      for (int dy = 0; dy < 3; ++dy) {
        const int  ro    = (dy == 2) ? ro2 : dy * WW;
        const bool okRow = (dy < 2) || okB;
        const float* r = p + ro;
        // middle 2*CPT cols are always in-bounds; only row2 & extra col masked
        if constexpr (CPT == 4) {
          float4 m0 = *(const float4*)r;
          float4 m1 = *(const float4*)(r + 4);
          v[dy][0]=m0.x; v[dy][1]=m0.y; v[dy][2]=m0.z; v[dy][3]=m0.w;
          v[dy][4]=m1.x; v[dy][5]=m1.y; v[dy][6]=m1.z; v[dy][7]=m1.w;
        } else if constexpr (CPT == 2) {
          float4 m0 = *(const float4*)r;
          v[dy][0]=m0.x; v[dy][1]=m0.y; v[dy][2]=m0.z; v[dy][3]=m0.w;
        } else {
          float2 m0 = *(const float2*)r;
          v[dy][0]=m0.x; v[dy][1]=m0.y;
        }
        if (!okRow) {
#pragma unroll
          for (int t = 0; t < 2 * CPT; ++t) v[dy][t] = 0.f;
        }
        float rf = r[xro];
        v[dy][2 * CPT] = (okRow && okR) ? rf : 0.f;
      }
      fma_all(ci);
    }
  }

#pragma unroll
  for (int u = 0; u < NC; ++u) {
    const float bv = bias[co0 + u];
    float* op = out + ((size_t)(b * COUT + co0 + u) * Ho + y) * Wo + x0;
    if constexpr (CPT == 4) {
      float4 r4;
      r4.x = act_fn<ACT>(acc[u][0] + bv); r4.y = act_fn<ACT>(acc[u][1] + bv);
      r4.z = act_fn<ACT>(acc[u][2] + bv); r4.w = act_fn<ACT>(acc[u][3] + bv);
      *(float4*)op = r4;
    } else if constexpr (CPT == 2) {
      float2 r2;
      r2.x = act_fn<ACT>(acc[u][0] + bv); r2.y = act_fn<ACT>(acc[u][1] + bv);
      *(float2*)op = r2;
    } else {
      op[0] = act_fn<ACT>(acc[u][0] + bv);
    }
  }
}

// ---------------- stride-2 3x3 SAME transposed conv ----------------------------
// out[2i,2j]=xtl*w00+xtr*w02+xbl*w20+xbr*w22; out[2i,2j+1]=xtr*w01+xbr*w21
// out[2i+1,2j]=xbl*w10+xbr*w12;               out[2i+1,2j+1]=xbr*w11
template<int ACT, int NC, int CIN, int COUT, int HIN>
__global__ __launch_bounds__(256)
void tconv(const float* __restrict__ in, const float* __restrict__ w,
           const float* __restrict__ bias, float* __restrict__ out) {
  constexpr int cogs = COUT / NC;
  constexpr int items = HIN * HIN;
  const int gx  = blockIdx.x;
  const int cog = gx % cogs;
  const int b   = gx / cogs;
  const int co0 = cog * NC;
  const int item = blockIdx.y * 256 + threadIdx.x;
  const int i = item / HIN;
  const int j = item - i * HIN;
  const float* bp = in + (size_t)b * CIN * items + i * HIN + j;

  float a00[NC], a01[NC], a10[NC], a11[NC];
#pragma unroll
  for (int u = 0; u < NC; ++u) { a00[u]=0.f; a01[u]=0.f; a10[u]=0.f; a11[u]=0.f; }

  auto fmab = [&](float xtl, float xtr, float xbl, float xbr, int ci) {
#pragma unroll
    for (int u = 0; u < NC; ++u) {
      const float* q = w + ((size_t)(co0 + u) * CIN + ci) * 9;
      a00[u] = fmaf(xtl, q[0], a00[u]);
      a00[u] = fmaf(xtr, q[2], a00[u]);
      a00[u] = fmaf(xbl, q[6], a00[u]);
      a00[u] = fmaf(xbr, q[8], a00[u]);
      a01[u] = fmaf(xtr, q[1], a01[u]);
      a01[u] = fmaf(xbr, q[7], a01[u]);
      a10[u] = fmaf(xbl, q[3], a10[u]);
      a10[u] = fmaf(xbr, q[5], a10[u]);
      a11[u] = fmaf(xbr, q[4], a11[u]);
    }
  };

  if (i > 0 && j > 0) {
    for (int ci = 0; ci < CIN; ++ci) {
      const float* p = bp + (size_t)ci * items;
      fmab(p[-HIN - 1], p[-HIN], p[-1], p[0], ci);
    }
  } else {
    const bool okT = (i > 0), okL = (j > 0);
    const int to = okT ? -HIN : 0;
    const int lo = okL ? -1 : 0;
    for (int ci = 0; ci < CIN; ++ci) {
      const float* p = bp + (size_t)ci * items;
      float xtl = p[to + lo]; xtl = (okT && okL) ? xtl : 0.f;
      float xtr = p[to];      xtr = okT ? xtr : 0.f;
      float xbl = p[lo];      xbl = okL ? xbl : 0.f;
      float xbr = p[0];
      fmab(xtl, xtr, xbl, xbr, ci);
    }
  }

  constexpr int Ho = HIN * 2;
#pragma unroll
  for (int u = 0; u < NC; ++u) {
    const float bv = bias[co0 + u];
    float* op = out + (size_t)(b * COUT + co0 + u) * Ho * Ho + (2 * i) * Ho + 2 * j;
    float2 t0, t1;
    t0.x = act_fn<ACT>(a00[u] + bv); t0.y = act_fn<ACT>(a01[u] + bv);
    t1.x = act_fn<ACT>(a10[u] + bv); t1.y = act_fn<ACT>(a11[u] + bv);
    *(float2*)op = t0;
    *(float2*)(op + Ho) = t1;
  }
}

// ---------------- keypoint reductions ------------------------------------------
__global__ __launch_bounds__(64)
void kp_reduce(const float* __restrict__ R, float* __restrict__ S,
               float* __restrict__ Sh, float* __restrict__ Sw) {
  const int bk = blockIdx.x;
  const int t = threadIdx.x;
  const float* p = R + (size_t)bk * 256;
  float s = 0.f, sh = 0.f, sw = 0.f;
#pragma unroll
  for (int q = 0; q < 4; ++q) {
    int idx = t + q * 64;
    float v = p[idx];
    s  += v;
    sh += v * (float)(idx >> 4);
    sw += v * (float)(idx & 15);
  }
#pragma unroll
  for (int off = 32; off > 0; off >>= 1) {
    s  += __shfl_down(s, off);
    sh += __shfl_down(sh, off);
    sw += __shfl_down(sw, off);
  }
  if (t == 0) { S[bk] = s; Sh[bk] = sh; Sw[bk] = sw; }
}

__global__ __launch_bounds__(256)
void kp_maps(const float* __restrict__ S, const float* __restrict__ Sh,
             const float* __restrict__ Sw, float* __restrict__ maps, int K) {
  const int bk = blockIdx.x;
  const int b = bk / K;
  const int t = threadIdx.x;
  const float s   = S[bk];
  const float den = S[b * K + (K - 1)];
  const float mu  = s * (1.0f / 256.0f);
  const float c0  = Sh[bk] / den;
  const float c1  = Sw[bk] / den;
  const float u = (float)(t >> 4);
  const float v = (float)(t & 15);
  const float d2 = (u - c0) * (u - c0) + (v - c1) * (v - c1);
  maps[(size_t)bk * 256 + t] = mu * expf(-0.5f * d2);
}

extern "C" void kernel_launch(void* const* d_in, const int* in_sizes, int n_in,
                              void* d_out, int out_size, void* d_ws, size_t ws_size,
                              hipStream_t stream) {
  const int B = 32;  // 4 * 8
  const float* x = (const float*)d_in[0];
  const float* ew[7]; const float* eb[7];
  for (int j = 0; j < 7; ++j) { ew[j] = (const float*)d_in[1 + 2*j]; eb[j] = (const float*)d_in[2 + 2*j]; }
  const float* dw[6]; const float* db[6];
  for (int j = 0; j < 6; ++j) { dw[j] = (const float*)d_in[15 + 2*j]; db[j] = (const float*)d_in[16 + 2*j]; }

  float* ws   = (float*)d_ws;
  float* bufA = ws;                       // 16,777,216 floats
  float* bufB = bufA + 16777216;
  float* R    = bufB + 16777216;          // 1,048,576
  float* maps = R + 1048576;
  float* S    = maps + 1048576;           // 4096
  float* Sh   = S + 4096;
  float* Sw   = Sh + 4096;
  float* outp = (float*)d_out;

  dim3 blk(256);

  // ---- encoder ----  grid.x = B*(Cout/NC), grid.y = H*(W/CPT)/256
  conv_s1<ACT_ID,      8,4,  3, 32,128,128><<<dim3(B*4, 16), blk, 0, stream>>>(x,    ew[0], eb[0], bufA);
  conv_s1<ACT_ID,      8,4, 32, 32,128,128><<<dim3(B*4, 16), blk, 0, stream>>>(bufA, ew[1], eb[1], bufB);
  conv_s2<ACT_LRELU,   8,4, 32, 64,128,128><<<dim3(B*8,  4), blk, 0, stream>>>(bufB, ew[2], eb[2], bufA);
  conv_s1<ACT_LRELU,   8,4, 64, 64, 64, 64><<<dim3(B*8,  4), blk, 0, stream>>>(bufA, ew[3], eb[3], bufB);
  conv_s2<ACT_LRELU,   8,2, 64,128, 64, 64><<<dim3(B*16, 2), blk, 0, stream>>>(bufB, ew[4], eb[4], bufA);
  conv_s1<ACT_LRELU,   8,2,128,128, 32, 32><<<dim3(B*16, 2), blk, 0, stream>>>(bufA, ew[5], eb[5], bufB);
  conv_s2<ACT_SOFTPLUS,4,1,128,128, 32, 32><<<dim3(B*32, 1), blk, 0, stream>>>(bufB, ew[6], eb[6], R);

  // ---- keypoint bottleneck ----
  kp_reduce<<<dim3(B*128), dim3(64), 0, stream>>>(R, S, Sh, Sw);
  kp_maps  <<<dim3(B*128), blk, 0, stream>>>(S, Sh, Sw, maps, 128);

  // ---- decoder ----
  tconv<ACT_RELU,2,128, 64,16><<<dim3(B*32, 1), blk, 0, stream>>>(maps, dw[0], db[0], bufA);
  conv_s1<ACT_RELU,4,2, 64, 64, 32, 32><<<dim3(B*16, 2), blk, 0, stream>>>(bufA, dw[1], db[1], bufB);
  tconv<ACT_RELU,4, 64, 32,32><<<dim3(B*8,  4), blk, 0, stream>>>(bufB, dw[2], db[2], bufA);
  conv_s1<ACT_RELU,8,2, 32, 32, 64, 64><<<dim3(B*4,  8), blk, 0, stream>>>(bufA, dw[3], db[3], bufB);
  tconv<ACT_RELU,8, 32, 16,64><<<dim3(B*2, 16), blk, 0, stream>>>(bufB, dw[4], db[4], bufA);
  conv_s1<ACT_RELU,8,4, 16, 16,128,128><<<dim3(B*2, 16), blk, 0, stream>>>(bufA, dw[5], db[5], outp);
}

// Round 8
// 1405.906 us; speedup vs baseline: 5.1266x; 1.0829x over previous
//
#include <hip/hip_runtime.h>
#include <math.h>

// ULOSD keypoint autoencoder, fp32 direct convolutions.
// Round 8 = round 7 (fmaf chains, compile-time shapes, interior fast path)
//         + round 5 (explicit register double-buffer prefetch of next-ci)
//         + split-K (e5 K2, e6 K2, d1 K4) so every grid >= 1024 blocks.
// r7 evidence: VGPR=32 -> no compiler pipelining -> exposed vmcnt stall per ci.
// r5 evidence: explicit prefetch hides it (e5 281 -> ~225 even with worse mix).

enum { ACT_ID = 0, ACT_LRELU = 1, ACT_SOFTPLUS = 2, ACT_RELU = 3 };

template<int ACT>
__device__ __forceinline__ float act_fn(float x) {
  if (ACT == ACT_LRELU)    return x >= 0.f ? x : 0.2f * x;
  if (ACT == ACT_SOFTPLUS) return fmaxf(x, 0.f) + log1pf(expf(-fabsf(x)));
  if (ACT == ACT_RELU)     return fmaxf(x, 0.f);
  return x;
}

// ---------------- stride-1 3x3 SAME conv, NC couts x CPT cols per thread -------
template<int ACT, int NC, int CPT, int KS, int CIN, int COUT, int HH, int WW>
__global__ __launch_bounds__(256)
void conv_s1(const float* __restrict__ in, const float* __restrict__ w,
             const float* __restrict__ bias, float* __restrict__ out,
             size_t kstride) {
  constexpr int cogs = COUT / NC;
  constexpr int HW = HH * WW;
  constexpr int Wq = WW / CPT;
  constexpr int nci = CIN / KS;
  constexpr int RV = CPT + 2;
  const int gx  = blockIdx.x;
  const int cog = gx % cogs;
  const int b   = gx / cogs;
  const int co0 = cog * NC;
  const int item = blockIdx.y * 256 + threadIdx.x;
  if (item >= HH * Wq) return;
  const int y  = item / Wq;
  const int x0 = (item - y * Wq) * CPT;
  const int ci0 = (KS > 1) ? (int)blockIdx.z * nci : 0;
  const float* bp = in + (size_t)b * CIN * HW + (size_t)ci0 * HW + y * WW + x0;

  float acc[NC][CPT];
#pragma unroll
  for (int u = 0; u < NC; ++u) {
#pragma unroll
    for (int q = 0; q < CPT; ++q) acc[u][q] = 0.f;
  }

  float va[3][RV], vb[3][RV];

  auto fma_all = [&](float v[3][RV], int ci) {
#pragma unroll
    for (int u = 0; u < NC; ++u) {
      const float* q = w + ((size_t)(co0 + u) * CIN + ci) * 9;
#pragma unroll
      for (int dy = 0; dy < 3; ++dy) {
        const float w0 = q[dy * 3], w1 = q[dy * 3 + 1], w2 = q[dy * 3 + 2];
#pragma unroll
        for (int t = 0; t < CPT; ++t) {
          acc[u][t] = fmaf(v[dy][t],     w0, acc[u][t]);
          acc[u][t] = fmaf(v[dy][t + 1], w1, acc[u][t]);
          acc[u][t] = fmaf(v[dy][t + 2], w2, acc[u][t]);
        }
      }
    }
  };

  const bool okT = (y > 0), okB = (y < HH - 1);
  const bool okL = (x0 > 0), okR = (x0 + CPT < WW);

  if (okT && okB && okL && okR) {
    // ---- interior: raw loads, immediate offsets, no masks, ci+1 prefetch ----
    auto load_i = [&](float v[3][RV], int k) {
      const float* p = bp + (size_t)k * HW;
#pragma unroll
      for (int dy = 0; dy < 3; ++dy) {
        const float* r = p + (dy - 1) * WW;
        v[dy][0] = r[-1];
        if constexpr (CPT == 4) {
          float4 m = *(const float4*)r;
          v[dy][1] = m.x; v[dy][2] = m.y; v[dy][3] = m.z; v[dy][4] = m.w;
        } else if constexpr (CPT == 2) {
          float2 m = *(const float2*)r;
          v[dy][1] = m.x; v[dy][2] = m.y;
        } else {
          v[dy][1] = r[0];
        }
        v[dy][CPT + 1] = r[CPT];
      }
    };
    load_i(va, 0);
    int k = 0;
    while (true) {
      if (k + 1 < nci) load_i(vb, k + 1);
      fma_all(va, ci0 + k);
      ++k; if (k >= nci) break;
      if (k + 1 < nci) load_i(va, k + 1);
      fma_all(vb, ci0 + k);
      ++k; if (k >= nci) break;
    }
  } else {
    // ---- boundary: clamped addresses, masks at use, ci+1 prefetch ----
    const int ro0 = okT ? -WW : 0;
    const int ro2 = okB ?  WW : 0;
    const int xlo = okL ? -1 : 0;
    const int xro = okR ? CPT : 0;
    auto load_b = [&](float v[3][RV], int k) {
      const float* p = bp + (size_t)k * HW;
#pragma unroll
      for (int dy = 0; dy < 3; ++dy) {
        const int ro = (dy == 0) ? ro0 : ((dy == 1) ? 0 : ro2);
        const float* r = p + ro;
        v[dy][0] = r[xlo];
#pragma unroll
        for (int t = 0; t < CPT; ++t) v[dy][1 + t] = r[t];
        v[dy][CPT + 1] = r[xro];
      }
    };
    auto mask_b = [&](float v[3][RV]) {
#pragma unroll
      for (int dy = 0; dy < 3; ++dy) {
        const bool okRow = (dy == 0) ? okT : ((dy == 1) ? true : okB);
        v[dy][0] = (okRow && okL) ? v[dy][0] : 0.f;
#pragma unroll
        for (int t = 1; t <= CPT; ++t) v[dy][t] = okRow ? v[dy][t] : 0.f;
        v[dy][CPT + 1] = (okRow && okR) ? v[dy][CPT + 1] : 0.f;
      }
    };
    load_b(va, 0);
    int k = 0;
    while (true) {
      if (k + 1 < nci) load_b(vb, k + 1);
      mask_b(va); fma_all(va, ci0 + k);
      ++k; if (k >= nci) break;
      if (k + 1 < nci) load_b(va, k + 1);
      mask_b(vb); fma_all(vb, ci0 + k);
      ++k; if (k >= nci) break;
    }
  }

  float* ob = out + ((KS > 1) ? (size_t)blockIdx.z * kstride : 0);
#pragma unroll
  for (int u = 0; u < NC; ++u) {
    float* op = ob + ((size_t)(b * COUT + co0 + u) * HH + y) * WW + x0;
    if constexpr (KS > 1) {
      if constexpr (CPT == 4) {
        float4 r4 = {acc[u][0], acc[u][1], acc[u][2], acc[u][3]};
        *(float4*)op = r4;
      } else if constexpr (CPT == 2) {
        float2 r2 = {acc[u][0], acc[u][1]};
        *(float2*)op = r2;
      } else {
        op[0] = acc[u][0];
      }
    } else {
      const float bv = bias[co0 + u];
      if constexpr (CPT == 4) {
        float4 r4;
        r4.x = act_fn<ACT>(acc[u][0] + bv); r4.y = act_fn<ACT>(acc[u][1] + bv);
        r4.z = act_fn<ACT>(acc[u][2] + bv); r4.w = act_fn<ACT>(acc[u][3] + bv);
        *(float4*)op = r4;
      } else if constexpr (CPT == 2) {
        float2 r2;
        r2.x = act_fn<ACT>(acc[u][0] + bv); r2.y = act_fn<ACT>(acc[u][1] + bv);
        *(float2*)op = r2;
      } else {
        op[0] = act_fn<ACT>(acc[u][0] + bv);
      }
    }
  }
}

// ---------------- stride-2 3x3 SAME conv (pad_before=0, pad_after=1) -----------
template<int ACT, int NC, int CPT, int KS, int CIN, int COUT, int HH, int WW>
__global__ __launch_bounds__(256)
void conv_s2(const float* __restrict__ in, const float* __restrict__ w,
             const float* __restrict__ bias, float* __restrict__ out,
             size_t kstride) {
  constexpr int Ho = HH / 2, Wo = WW / 2;
  constexpr int cogs = COUT / NC;
  constexpr int HW = HH * WW;
  constexpr int Wq = Wo / CPT;
  constexpr int nci = CIN / KS;
  constexpr int RV = 2 * CPT + 1;
  const int gx  = blockIdx.x;
  const int cog = gx % cogs;
  const int b   = gx / cogs;
  const int co0 = cog * NC;
  const int item = blockIdx.y * 256 + threadIdx.x;
  if (item >= Ho * Wq) return;
  const int y  = item / Wq;
  const int x0 = (item - y * Wq) * CPT;
  const int ix = 2 * x0;
  const int ci0 = (KS > 1) ? (int)blockIdx.z * nci : 0;
  const float* bp = in + (size_t)b * CIN * HW + (size_t)ci0 * HW + (2 * y) * WW + ix;

  float acc[NC][CPT];
#pragma unroll
  for (int u = 0; u < NC; ++u) {
#pragma unroll
    for (int q = 0; q < CPT; ++q) acc[u][q] = 0.f;
  }

  float va[3][RV], vb[3][RV];

  auto fma_all = [&](float v[3][RV], int ci) {
#pragma unroll
    for (int u = 0; u < NC; ++u) {
      const float* q = w + ((size_t)(co0 + u) * CIN + ci) * 9;
#pragma unroll
      for (int dy = 0; dy < 3; ++dy) {
        const float w0 = q[dy * 3], w1 = q[dy * 3 + 1], w2 = q[dy * 3 + 2];
#pragma unroll
        for (int t = 0; t < CPT; ++t) {
          acc[u][t] = fmaf(v[dy][2 * t],     w0, acc[u][t]);
          acc[u][t] = fmaf(v[dy][2 * t + 1], w1, acc[u][t]);
          acc[u][t] = fmaf(v[dy][2 * t + 2], w2, acc[u][t]);
        }
      }
    }
  };

  const bool okB = (2 * y + 2 < HH);
  const bool okR = (ix + 2 * CPT < WW);

  auto load_mid = [&](float v[3][RV], const float* p, int ro2, int xro) {
#pragma unroll
    for (int dy = 0; dy < 3; ++dy) {
      const int ro = (dy == 2) ? ro2 : dy * WW;
      const float* r = p + ro;
      if constexpr (CPT == 4) {
        float4 m0 = *(const float4*)r;
        float4 m1 = *(const float4*)(r + 4);
        v[dy][0]=m0.x; v[dy][1]=m0.y; v[dy][2]=m0.z; v[dy][3]=m0.w;
        v[dy][4]=m1.x; v[dy][5]=m1.y; v[dy][6]=m1.z; v[dy][7]=m1.w;
      } else if constexpr (CPT == 2) {
        float4 m0 = *(const float4*)r;
        v[dy][0]=m0.x; v[dy][1]=m0.y; v[dy][2]=m0.z; v[dy][3]=m0.w;
      } else {
        float2 m0 = *(const float2*)r;
        v[dy][0]=m0.x; v[dy][1]=m0.y;
      }
      v[dy][2 * CPT] = r[xro];
    }
  };

  if (okB && okR) {
    auto load_i = [&](float v[3][RV], int k) {
      load_mid(v, bp + (size_t)k * HW, 2 * WW, 2 * CPT);
    };
    load_i(va, 0);
    int k = 0;
    while (true) {
      if (k + 1 < nci) load_i(vb, k + 1);
      fma_all(va, ci0 + k);
      ++k; if (k >= nci) break;
      if (k + 1 < nci) load_i(va, k + 1);
      fma_all(vb, ci0 + k);
      ++k; if (k >= nci) break;
    }
  } else {
    const int ro2 = okB ? 2 * WW : 0;
    const int xro = okR ? 2 * CPT : 0;
    auto load_b = [&](float v[3][RV], int k) {
      load_mid(v, bp + (size_t)k * HW, ro2, xro);
    };
    auto mask_b = [&](float v[3][RV]) {
      if (!okB) {
#pragma unroll
        for (int t = 0; t < 2 * CPT; ++t) v[2][t] = 0.f;
      }
#pragma unroll
      for (int dy = 0; dy < 3; ++dy) {
        const bool okRow = (dy < 2) || okB;
        v[dy][2 * CPT] = (okRow && okR) ? v[dy][2 * CPT] : 0.f;
      }
    };
    load_b(va, 0);
    int k = 0;
    while (true) {
      if (k + 1 < nci) load_b(vb, k + 1);
      mask_b(va); fma_all(va, ci0 + k);
      ++k; if (k >= nci) break;
      if (k + 1 < nci) load_b(va, k + 1);
      mask_b(vb); fma_all(vb, ci0 + k);
      ++k; if (k >= nci) break;
    }
  }

  float* ob = out + ((KS > 1) ? (size_t)blockIdx.z * kstride : 0);
#pragma unroll
  for (int u = 0; u < NC; ++u) {
    float* op = ob + ((size_t)(b * COUT + co0 + u) * Ho + y) * Wo + x0;
    if constexpr (KS > 1) {
      if constexpr (CPT == 4) {
        float4 r4 = {acc[u][0], acc[u][1], acc[u][2], acc[u][3]};
        *(float4*)op = r4;
      } else if constexpr (CPT == 2) {
        float2 r2 = {acc[u][0], acc[u][1]};
        *(float2*)op = r2;
      } else {
        op[0] = acc[u][0];
      }
    } else {
      const float bv = bias[co0 + u];
      if constexpr (CPT == 4) {
        float4 r4;
        r4.x = act_fn<ACT>(acc[u][0] + bv); r4.y = act_fn<ACT>(acc[u][1] + bv);
        r4.z = act_fn<ACT>(acc[u][2] + bv); r4.w = act_fn<ACT>(acc[u][3] + bv);
        *(float4*)op = r4;
      } else if constexpr (CPT == 2) {
        float2 r2;
        r2.x = act_fn<ACT>(acc[u][0] + bv); r2.y = act_fn<ACT>(acc[u][1] + bv);
        *(float2*)op = r2;
      } else {
        op[0] = act_fn<ACT>(acc[u][0] + bv);
      }
    }
  }
}

// ---------------- stride-2 3x3 SAME transposed conv ----------------------------
template<int ACT, int NC, int CIN, int COUT, int HIN>
__global__ __launch_bounds__(256)
void tconv(const float* __restrict__ in, const float* __restrict__ w,
           const float* __restrict__ bias, float* __restrict__ out) {
  constexpr int cogs = COUT / NC;
  constexpr int items = HIN * HIN;
  const int gx  = blockIdx.x;
  const int cog = gx % cogs;
  const int b   = gx / cogs;
  const int co0 = cog * NC;
  const int item = blockIdx.y * 256 + threadIdx.x;
  if (item >= items) return;
  const int i = item / HIN;
  const int j = item - i * HIN;
  const float* bp = in + (size_t)b * CIN * items + i * HIN + j;

  float a00[NC], a01[NC], a10[NC], a11[NC];
#pragma unroll
  for (int u = 0; u < NC; ++u) { a00[u]=0.f; a01[u]=0.f; a10[u]=0.f; a11[u]=0.f; }

  const bool okT = (i > 0), okL = (j > 0);
  const int to = okT ? -HIN : 0;
  const int lo = okL ? -1 : 0;

  auto load4 = [&](float* v, int ci) {
    const float* p = bp + (size_t)ci * items;
    v[0] = p[to + lo];
    v[1] = p[to];
    v[2] = p[lo];
    v[3] = p[0];
  };
  auto fma4 = [&](float* v, int ci) {
    float xtl = (okT && okL) ? v[0] : 0.f;
    float xtr = okT ? v[1] : 0.f;
    float xbl = okL ? v[2] : 0.f;
    float xbr = v[3];
#pragma unroll
    for (int u = 0; u < NC; ++u) {
      const float* q = w + ((size_t)(co0 + u) * CIN + ci) * 9;
      a00[u] = fmaf(xtl, q[0], a00[u]);
      a00[u] = fmaf(xtr, q[2], a00[u]);
      a00[u] = fmaf(xbl, q[6], a00[u]);
      a00[u] = fmaf(xbr, q[8], a00[u]);
      a01[u] = fmaf(xtr, q[1], a01[u]);
      a01[u] = fmaf(xbr, q[7], a01[u]);
      a10[u] = fmaf(xbl, q[3], a10[u]);
      a10[u] = fmaf(xbr, q[5], a10[u]);
      a11[u] = fmaf(xbr, q[4], a11[u]);
    }
  };

  float va[4], vb[4];
  load4(va, 0);
  int ci = 0;
  while (true) {
    if (ci + 1 < CIN) load4(vb, ci + 1);
    fma4(va, ci);
    ++ci; if (ci >= CIN) break;
    if (ci + 1 < CIN) load4(va, ci + 1);
    fma4(vb, ci);
    ++ci; if (ci >= CIN) break;
  }

  constexpr int Ho = HIN * 2;
#pragma unroll
  for (int u = 0; u < NC; ++u) {
    const float bv = bias[co0 + u];
    float* op = out + (size_t)(b * COUT + co0 + u) * Ho * Ho + (2 * i) * Ho + 2 * j;
    float2 t0, t1;
    t0.x = act_fn<ACT>(a00[u] + bv); t0.y = act_fn<ACT>(a01[u] + bv);
    t1.x = act_fn<ACT>(a10[u] + bv); t1.y = act_fn<ACT>(a11[u] + bv);
    *(float2*)op = t0;
    *(float2*)(op + Ho) = t1;
  }
}

// ---------------- split-K combine epilogues ------------------------------------
template<int ACT>
__global__ __launch_bounds__(256)
void combine2(const float* __restrict__ P0, const float* __restrict__ P1,
              const float* __restrict__ bias, float* __restrict__ out,
              int C, int HW, int n4) {
  const int i = blockIdx.x * 256 + threadIdx.x;
  if (i >= n4) return;
  const int e = i * 4;
  const int c = (e / HW) % C;
  float4 a = ((const float4*)P0)[i];
  float4 b = ((const float4*)P1)[i];
  const float bv = bias[c];
  float4 r;
  r.x = act_fn<ACT>(a.x + b.x + bv);
  r.y = act_fn<ACT>(a.y + b.y + bv);
  r.z = act_fn<ACT>(a.z + b.z + bv);
  r.w = act_fn<ACT>(a.w + b.w + bv);
  ((float4*)out)[i] = r;
}

template<int ACT>
__global__ __launch_bounds__(256)
void combine4(const float* __restrict__ P, const float* __restrict__ bias,
              float* __restrict__ out, int C, int HW, int n4, int ks4) {
  const int i = blockIdx.x * 256 + threadIdx.x;
  if (i >= n4) return;
  const int e = i * 4;
  const int c = (e / HW) % C;
  float4 a0 = ((const float4*)P)[i];
  float4 a1 = ((const float4*)P)[i + ks4];
  float4 a2 = ((const float4*)P)[i + 2 * ks4];
  float4 a3 = ((const float4*)P)[i + 3 * ks4];
  const float bv = bias[c];
  float4 r;
  r.x = act_fn<ACT>(a0.x + a1.x + a2.x + a3.x + bv);
  r.y = act_fn<ACT>(a0.y + a1.y + a2.y + a3.y + bv);
  r.z = act_fn<ACT>(a0.z + a1.z + a2.z + a3.z + bv);
  r.w = act_fn<ACT>(a0.w + a1.w + a2.w + a3.w + bv);
  ((float4*)out)[i] = r;
}

// ---------------- keypoint reductions ------------------------------------------
__global__ __launch_bounds__(64)
void kp_reduce(const float* __restrict__ R, float* __restrict__ S,
               float* __restrict__ Sh, float* __restrict__ Sw) {
  const int bk = blockIdx.x;
  const int t = threadIdx.x;
  const float* p = R + (size_t)bk * 256;
  float s = 0.f, sh = 0.f, sw = 0.f;
#pragma unroll
  for (int q = 0; q < 4; ++q) {
    int idx = t + q * 64;
    float v = p[idx];
    s  += v;
    sh += v * (float)(idx >> 4);
    sw += v * (float)(idx & 15);
  }
#pragma unroll
  for (int off = 32; off > 0; off >>= 1) {
    s  += __shfl_down(s, off);
    sh += __shfl_down(sh, off);
    sw += __shfl_down(sw, off);
  }
  if (t == 0) { S[bk] = s; Sh[bk] = sh; Sw[bk] = sw; }
}

__global__ __launch_bounds__(256)
void kp_maps(const float* __restrict__ S, const float* __restrict__ Sh,
             const float* __restrict__ Sw, float* __restrict__ maps, int K) {
  const int bk = blockIdx.x;
  const int b = bk / K;
  const int t = threadIdx.x;
  const float s   = S[bk];
  const float den = S[b * K + (K - 1)];
  const float mu  = s * (1.0f / 256.0f);
  const float c0  = Sh[bk] / den;
  const float c1  = Sw[bk] / den;
  const float u = (float)(t >> 4);
  const float v = (float)(t & 15);
  const float d2 = (u - c0) * (u - c0) + (v - c1) * (v - c1);
  maps[(size_t)bk * 256 + t] = mu * expf(-0.5f * d2);
}

extern "C" void kernel_launch(void* const* d_in, const int* in_sizes, int n_in,
                              void* d_out, int out_size, void* d_ws, size_t ws_size,
                              hipStream_t stream) {
  const int B = 32;  // 4 * 8
  const float* x = (const float*)d_in[0];
  const float* ew[7]; const float* eb[7];
  for (int j = 0; j < 7; ++j) { ew[j] = (const float*)d_in[1 + 2*j]; eb[j] = (const float*)d_in[2 + 2*j]; }
  const float* dw[6]; const float* db[6];
  for (int j = 0; j < 6; ++j) { dw[j] = (const float*)d_in[15 + 2*j]; db[j] = (const float*)d_in[16 + 2*j]; }

  float* ws   = (float*)d_ws;
  float* bufA = ws;                       // 16,777,216 floats
  float* bufB = bufA + 16777216;
  float* R    = bufB + 16777216;          // 1,048,576
  float* maps = R + 1048576;
  float* S    = maps + 1048576;           // 4096
  float* Sh   = S + 4096;
  float* Sw   = Sh + 4096;
  float* outp = (float*)d_out;

  dim3 blk(256);

  // ---- encoder ----
  conv_s1<ACT_ID,   8,4,1,  3, 32,128,128><<<dim3(B*4, 16), blk, 0, stream>>>(x,    ew[0], eb[0], bufA, 0);
  conv_s1<ACT_ID,   8,4,1, 32, 32,128,128><<<dim3(B*4, 16), blk, 0, stream>>>(bufA, ew[1], eb[1], bufB, 0);
  conv_s2<ACT_LRELU,8,4,1, 32, 64,128,128><<<dim3(B*8,  4), blk, 0, stream>>>(bufB, ew[2], eb[2], bufA, 0);
  conv_s1<ACT_LRELU,8,4,1, 64, 64, 64, 64><<<dim3(B*8,  4), blk, 0, stream>>>(bufA, ew[3], eb[3], bufB, 0);
  conv_s2<ACT_LRELU,8,2,1, 64,128, 64, 64><<<dim3(B*16, 2), blk, 0, stream>>>(bufB, ew[4], eb[4], bufA, 0);

  // e5: 128->128 @32x32, NC8/CPT4, split-K=2 -> 1024 blocks
  float* P5 = bufA + 8388608;             // input bufA uses [0, 4.19M); partials 2 x 4,194,304
  conv_s1<ACT_LRELU,8,4,2,128,128, 32, 32><<<dim3(B*16, 1, 2), blk, 0, stream>>>(bufA, ew[5], eb[5], P5, 4194304);
  combine2<ACT_LRELU><<<dim3(4096), blk, 0, stream>>>(P5, P5 + 4194304, eb[5], bufB, 128, 1024, 1048576);

  // e6: 128->128 s2 @32->16, NC8/CPT1, split-K=2 -> 1024 blocks
  float* P6 = bufA;                       // bufA fully dead; 2 x 1,048,576
  conv_s2<ACT_SOFTPLUS,8,1,2,128,128, 32, 32><<<dim3(B*16, 1, 2), blk, 0, stream>>>(bufB, ew[6], eb[6], P6, 1048576);
  combine2<ACT_SOFTPLUS><<<dim3(1024), blk, 0, stream>>>(P6, P6 + 1048576, eb[6], R, 128, 256, 262144);

  // ---- keypoint bottleneck ----
  kp_reduce<<<dim3(B*128), dim3(64), 0, stream>>>(R, S, Sh, Sw);
  kp_maps  <<<dim3(B*128), blk, 0, stream>>>(S, Sh, Sw, maps, 128);

  // ---- decoder ----
  tconv<ACT_RELU,2,128, 64,16><<<dim3(B*32, 1), blk, 0, stream>>>(maps, dw[0], db[0], bufA);

  // d1: 64->64 @32x32, NC8/CPT4, split-K=4 -> 1024 blocks
  float* PD1 = bufA + 2097152;            // d1 input uses [0, 2.1M); partials 4 x 2,097,152
  conv_s1<ACT_RELU,8,4,4, 64, 64, 32, 32><<<dim3(B*8, 1, 4), blk, 0, stream>>>(bufA, dw[1], db[1], PD1, 2097152);
  combine4<ACT_RELU><<<dim3(2048), blk, 0, stream>>>(PD1, db[1], bufB, 64, 1024, 524288, 524288);

  tconv<ACT_RELU,4, 64, 32,32><<<dim3(B*8,  4), blk, 0, stream>>>(bufB, dw[2], db[2], bufA);
  conv_s1<ACT_RELU,4,4,1, 32, 32, 64, 64><<<dim3(B*8,  4), blk, 0, stream>>>(bufA, dw[3], db[3], bufB, 0);
  tconv<ACT_RELU,8, 32, 16,64><<<dim3(B*2, 16), blk, 0, stream>>>(bufB, dw[4], db[4], bufA);
  conv_s1<ACT_RELU,8,4,1, 16, 16,128,128><<<dim3(B*2, 16), blk, 0, stream>>>(bufA, dw[5], db[5], outp, 0);
}